// Round 2
// baseline (3208.739 us; speedup 1.0000x reference)
//
#include <hip/hip_runtime.h>
#include <stdint.h>

typedef unsigned short u16;
typedef __attribute__((ext_vector_type(8))) short bfrag;   // 8 bf16 = 4 VGPR MFMA operand
typedef __attribute__((ext_vector_type(4))) float f32x4;   // MFMA accumulator

#define DEVI __device__ __forceinline__

DEVI float b2f(u16 u){ return __uint_as_float(((uint32_t)u) << 16); }
DEVI u16 f2b(float f){
  uint32_t x = __float_as_uint(f);
  uint32_t r = (x + 0x7fffu + ((x >> 16) & 1u)) >> 16;   // RNE
  return (u16)r;
}
DEVI float silu_f(float v){ return v / (1.0f + __expf(-v)); }

// ---- transposed-weight arena element offsets (bf16 elements) ----
#define OFF_KJ   0
#define OFF_DOWN 16384
#define OFF_JI   24576
#define OFF_UP   122880
#define OFF_BS1  172032
#define OFF_BS2  270336
#define OFF_LIN  368640
#define OFF_AS1  466944
#define OFF_AS2  565248
#define WT_TOTAL 663552

struct TW {
  const float *kj, *down, *ji, *up, *bs1, *bs2, *lin, *as1, *as2;
  u16* dst;
};

// Transpose+convert all weight matrices fp32 [K,N] -> bf16 [N,K] once.
__global__ void __launch_bounds__(256) k_transpose(TW p){
  int id = blockIdx.y;
  const float* src; int K, N; int doff;
  if      (id == 0) { src = p.kj;                K = 128; N = 128; doff = OFF_KJ; }
  else if (id == 1) { src = p.down;              K = 128; N = 64;  doff = OFF_DOWN; }
  else if (id < 8)  { int b = id - 2;  src = p.ji  + b*16384; K = 128; N = 128; doff = OFF_JI  + b*16384; }
  else if (id < 14) { int b = id - 8;  src = p.up  + b*8192;  K = 64;  N = 128; doff = OFF_UP  + b*8192;  }
  else if (id < 20) { int b = id - 14; src = p.bs1 + b*16384; K = 128; N = 128; doff = OFF_BS1 + b*16384; }
  else if (id < 26) { int b = id - 20; src = p.bs2 + b*16384; K = 128; N = 128; doff = OFF_BS2 + b*16384; }
  else if (id < 32) { int b = id - 26; src = p.lin + b*16384; K = 128; N = 128; doff = OFF_LIN + b*16384; }
  else if (id < 38) { int b = id - 32; src = p.as1 + b*16384; K = 128; N = 128; doff = OFF_AS1 + b*16384; }
  else              { int b = id - 38; src = p.as2 + b*16384; K = 128; N = 128; doff = OFF_AS2 + b*16384; }
  int idx = blockIdx.x*256 + threadIdx.x;
  if (idx >= K*N) return;
  int n = idx / K, k = idx - n*K;
  p.dst[doff + idx] = f2b(src[k*N + n]);
}

// elementwise fp32 -> bf16
__global__ void __launch_bounds__(256) k_f2b(
    const float* __restrict__ src, u16* __restrict__ dst, int n)
{
  int i = blockIdx.x*256 + threadIdx.x;
  if (i < n) dst[i] = f2b(src[i]);
}

// rbf2[e,h] = ((rbf @ W_rbf1) @ W_rbf2)[e,h]  (fp32 in, bf16 out)
__global__ void __launch_bounds__(256) k_rbf(
    const float* __restrict__ rbf, const float* __restrict__ W1,
    const float* __restrict__ W2, u16* __restrict__ out, int E)
{
  __shared__ float w1s[48];
  __shared__ float w2s[1024];
  for (int i = threadIdx.x; i < 48;   i += 256) w1s[i] = W1[i];
  for (int i = threadIdx.x; i < 1024; i += 256) w2s[i] = W2[i];
  __syncthreads();
  int idx = blockIdx.x*256 + threadIdx.x;
  if (idx >= E*128) return;
  int e = idx >> 7, h = idx & 127;
  float rv[6];
#pragma unroll
  for (int k = 0; k < 6; k++) rv[k] = rbf[e*6 + k];
  float o = 0.f;
#pragma unroll
  for (int j = 0; j < 8; j++){
    float m = 0.f;
#pragma unroll
    for (int k = 0; k < 6; k++) m += rv[k] * w1s[k*8 + j];
    o += m * w2s[j*128 + h];
  }
  out[idx] = f2b(o);
}

// s1[t,0:8] = (sbf @ W_sbf1)[t]  (fp32 in, fp32 out)
__global__ void __launch_bounds__(256) k_s1(
    const float* __restrict__ sbf, const float* __restrict__ W1,
    float* __restrict__ s1, int T)
{
  __shared__ float w1s[336];
  for (int i = threadIdx.x; i < 336; i += 256) w1s[i] = W1[i];
  __syncthreads();
  int t = blockIdx.x*256 + threadIdx.x;
  if (t >= T) return;
  const float* row = sbf + (size_t)t*42;
  float a[8];
#pragma unroll
  for (int j = 0; j < 8; j++) a[j] = 0.f;
  for (int k = 0; k < 42; k++){
    float sv = row[k];
#pragma unroll
    for (int j = 0; j < 8; j++) a[j] += sv * w1s[k*8 + j];
  }
#pragma unroll
  for (int j = 0; j < 8; j++) s1[(size_t)t*8 + j] = a[j];
}

// one wave per triplet: sbf_e = s1 @ W_sbf2; v = x_kj[idx_kj]*sbf_e; scatter into agg[branch]
__global__ void __launch_bounds__(256) k_triplet(
    const int* __restrict__ idx_kj, const int* __restrict__ idx_ji,
    const int* __restrict__ bt, const float* __restrict__ s1,
    const float* __restrict__ Wsbf2, const u16* __restrict__ xkj,
    float* __restrict__ agg, int T, int E)
{
  int g = blockIdx.x*256 + threadIdx.x;
  int t = g >> 6, lane = g & 63;
  if (t >= T) return;
  int kj = idx_kj[t], ji = idx_ji[t];
  int b = bt[kj] + 1;
  b = b < 0 ? 0 : (b > 5 ? 5 : b);
  float se = 0.f;
#pragma unroll
  for (int j = 0; j < 8; j++) se += s1[(size_t)t*8 + j] * Wsbf2[j*64 + lane];
  float v = b2f(xkj[(size_t)kj*64 + lane]) * se;
  unsafeAtomicAdd(&agg[((size_t)b*E + ji)*64 + lane], v);
}

// agg fp32 -> aggb bf16 slots 0..5, slot 6 = sum (== agg_gen)
__global__ void __launch_bounds__(256) k_cvt(
    const float* __restrict__ agg, u16* __restrict__ aggb, int EI)
{
  int idx = blockIdx.x*256 + threadIdx.x;
  if (idx >= EI) return;
  float s = 0.f;
#pragma unroll
  for (int b = 0; b < 6; b++){
    float v = agg[(size_t)b*EI + idx];
    s += v;
    aggb[(size_t)b*EI + idx] = f2b(v);
  }
  aggb[(size_t)6*EI + idx] = f2b(s);
}

// ---- fused-epilogue MFMA GEMM: C = epi(A[M,K] @ W[K,N]) ----
// WT is pre-transposed bf16 [N,K]. bias fp32, aux bf16, accF/outF fp32, outB bf16.
enum { EPI_MUL = 0, EPI_ADD = 1, EPI_ACC = 2, EPI_FIN = 3 };

template<int MODE, int N, int K>
__global__ void __launch_bounds__(256) k_gemm(
    const u16* __restrict__ A, const u16* __restrict__ WT,
    const float* __restrict__ bias, const u16* __restrict__ aux,
    float* __restrict__ accF, u16* __restrict__ outB,
    float* __restrict__ outF, const float* __restrict__ alphaPtr, int M)
{
  constexpr int KP = K + 8;             // +16B pad -> 2-way LDS aliasing (free)
  __shared__ __attribute__((aligned(16))) u16 lds[KP*N];
  const int tid = threadIdx.x;
  constexpr int CH = (N*K)/8;
  for (int c = tid; c < CH; c += 256){
    int n  = c / (K/8);
    int kc = (c - n*(K/8))*8;
    *(int4*)&lds[n*KP + kc] = *(const int4*)&WT[n*K + kc];
  }
  __syncthreads();

  const int wave = tid >> 6, lane = tid & 63;
  const int lr = lane & 15, lq = lane >> 4;
  const int m0 = blockIdx.x*128 + wave*32;
  constexpr int NBN = N/16;
  f32x4 acc[2][NBN];
#pragma unroll
  for (int i = 0; i < 2; i++)
#pragma unroll
    for (int j = 0; j < NBN; j++) acc[i][j] = (f32x4){0.f,0.f,0.f,0.f};

  const int r0 = m0 + lr;
#pragma unroll
  for (int ks = 0; ks < K/32; ks++){
    const int k0 = ks*32 + lq*8;
    bfrag a0 = {0,0,0,0,0,0,0,0}, a1 = {0,0,0,0,0,0,0,0};
    if (r0 < M)      a0 = *(const bfrag*)&A[(size_t)r0*K + k0];
    if (r0 + 16 < M) a1 = *(const bfrag*)&A[(size_t)(r0+16)*K + k0];
#pragma unroll
    for (int nb = 0; nb < NBN; nb++){
      bfrag bv = *(const bfrag*)&lds[(nb*16 + lr)*KP + k0];
      acc[0][nb] = __builtin_amdgcn_mfma_f32_16x16x32_bf16(a0, bv, acc[0][nb], 0, 0, 0);
      acc[1][nb] = __builtin_amdgcn_mfma_f32_16x16x32_bf16(a1, bv, acc[1][nb], 0, 0, 0);
    }
  }

  float sc = 0.f;
  if (MODE == EPI_ACC || MODE == EPI_FIN){
    float al = alphaPtr[0];
    sc = (MODE == EPI_FIN) ? al : (1.0f - al);
  }

#pragma unroll
  for (int mb = 0; mb < 2; mb++){
    const int rowb = m0 + mb*16 + lq*4;
#pragma unroll
    for (int nb = 0; nb < NBN; nb++){
      const int col = nb*16 + lr;
      const float bvv = bias ? bias[col] : 0.f;
#pragma unroll
      for (int r = 0; r < 4; r++){
        const int row = rowb + r;
        if (row >= M) continue;
        const size_t oi = (size_t)row*N + col;
        float v = silu_f(acc[mb][nb][r] + bvv);
        if (MODE == EPI_MUL){
          v *= b2f(aux[oi]);
          outB[oi] = f2b(v);
        } else if (MODE == EPI_ADD){
          if (aux) v += b2f(aux[oi]);
          outB[oi] = f2b(v);
        } else if (MODE == EPI_ACC){
          v += b2f(aux[oi]);
          accF[oi] += sc*v;
        } else {
          v += b2f(aux[oi]);
          outF[oi] = sc*v + accF[oi];
        }
      }
    }
  }
}

extern "C" void kernel_launch(void* const* d_in, const int* in_sizes, int n_in,
                              void* d_out, int out_size, void* d_ws, size_t ws_size,
                              hipStream_t stream)
{
  const float* x     = (const float*)d_in[0];
  const float* rbf   = (const float*)d_in[1];
  const float* sbf   = (const float*)d_in[2];
  const int*   ikj   = (const int*)d_in[3];
  const int*   iji   = (const int*)d_in[4];
  const int*   bt    = (const int*)d_in[5];
  const float* alphaP= (const float*)d_in[6];
  // d_in[7] = lambda_d (unused)
  const float* Wrbf1 = (const float*)d_in[8];
  const float* Wrbf2 = (const float*)d_in[9];
  const float* Wsbf1 = (const float*)d_in[10];
  const float* Wsbf2 = (const float*)d_in[11];
  const float* Wkj   = (const float*)d_in[12];
  const float* bkj   = (const float*)d_in[13];
  const float* Wji   = (const float*)d_in[14];
  const float* bji   = (const float*)d_in[15];
  const float* Wdown = (const float*)d_in[16];
  const float* Wup   = (const float*)d_in[17];
  const float* Wbs1  = (const float*)d_in[18];
  const float* bbs1  = (const float*)d_in[19];
  const float* Wbs2  = (const float*)d_in[20];
  const float* bbs2  = (const float*)d_in[21];
  const float* Wlin  = (const float*)d_in[22];
  const float* blin  = (const float*)d_in[23];
  const float* Was1  = (const float*)d_in[24];
  const float* bas1  = (const float*)d_in[25];
  const float* Was2  = (const float*)d_in[26];
  const float* bas2  = (const float*)d_in[27];

  const int E = in_sizes[5];      // bt is [E]
  const int T = in_sizes[3];      // idx_kj is [T]
  const int H = 128, I = 64;

  char* ws = (char*)d_ws;
  size_t off = 0;
  auto arena = [&](size_t bytes)->size_t{
    size_t o = off; off += (bytes + 255) & ~(size_t)255; return o;
  };
  size_t oWT   = arena((size_t)WT_TOTAL*2);   // 1.3 MB  transposed bf16 weights
  size_t oXB   = arena((size_t)E*H*2);        // 25.6 MB x in bf16
  size_t oR0   = arena((size_t)E*H*2);        // 25.6 MB temp (also s1: 19.2 MB fp32)
  size_t oR1   = arena((size_t)E*H*2);        // 25.6 MB temp
  size_t oXKJ  = arena((size_t)E*I*2);        // 12.8 MB x_kj bf16
  size_t oAGG  = arena((size_t)6*E*I*4);      // 153.6 MB fp32 scatter target (reused as ACC)
  size_t oAGGB = arena((size_t)7*E*I*2);      // 89.6 MB bf16 agg slots (6 = agg_gen)
  if (off > ws_size) return;                  // refuse to corrupt if ws too small

  u16*   WT   = (u16*)(ws + oWT);
  u16*   XB   = (u16*)(ws + oXB);
  u16*   R0   = (u16*)(ws + oR0);
  u16*   R1   = (u16*)(ws + oR1);
  u16*   XKJ  = (u16*)(ws + oXKJ);
  float* AGG  = (float*)(ws + oAGG);
  u16*   AGGB = (u16*)(ws + oAGGB);
  float* ACC  = (float*)(ws + oAGG);          // reuse AGG region after k_cvt
  float* S1   = (float*)(ws + oR0);           // reuse R0 window (rbf2 dead by then)

  TW tw{Wkj, Wdown, Wji, Wup, Wbs1, Wbs2, Wlin, Was1, Was2, WT};
  hipLaunchKernelGGL(k_transpose, dim3(64, 44, 1), dim3(256, 1, 1), 0, stream, tw);

  const int mt = (E + 127)/128;

  // x -> bf16
  k_f2b<<<dim3((E*H + 255)/256), dim3(256), 0, stream>>>(x, XB, E*H);
  // rbf2 -> R0 (bf16)
  k_rbf<<<dim3((E*128 + 255)/256), dim3(256), 0, stream>>>(rbf, Wrbf1, Wrbf2, R0, E);
  // t = silu(x@W_kj + b_kj) * rbf2 -> R1
  k_gemm<EPI_MUL,128,128><<<dim3(mt), dim3(256), 0, stream>>>(XB, WT + OFF_KJ, bkj, R0, nullptr, R1, nullptr, nullptr, E);
  // x_kj = silu(t@W_down) -> XKJ
  k_gemm<EPI_ADD,64,128><<<dim3(mt), dim3(256), 0, stream>>>(R1, WT + OFF_DOWN, nullptr, nullptr, nullptr, XKJ, nullptr, nullptr, E);
  // s1 = sbf@W_sbf1 -> S1 (in R0; rbf2 consumed by EPI_MUL above)
  k_s1<<<dim3((T + 255)/256), dim3(256), 0, stream>>>(sbf, Wsbf1, S1, T);
  // zero agg, scatter triplets
  hipMemsetAsync(ws + oAGG, 0, (size_t)6*E*I*4, stream);
  k_triplet<<<dim3(((size_t)T*64 + 255)/256), dim3(256), 0, stream>>>(ikj, iji, bt, S1, Wsbf2, XKJ, AGG, T, E);
  // bf16 agg slots + generic sum
  k_cvt<<<dim3((E*I + 255)/256), dim3(256), 0, stream>>>(AGG, AGGB, E*I);
  // zero fp32 output accumulator (first 51.2 MB of AGG region; AGG dead after k_cvt)
  hipMemsetAsync(ws + oAGG, 0, (size_t)E*H*4, stream);

  // 7 chains: branches 0..5 accumulate (1-alpha)*h_b into ACC; chain 6 = generic
  // (weights b=5, agg slot 6) writes d_out = alpha*h_gen + ACC.
  for (int c = 0; c < 7; c++){
    const int b    = (c < 6) ? c : 5;
    const int slot = (c < 6) ? c : 6;
    const u16* aggA = AGGB + (size_t)slot*E*I;
    // t1 = silu(agg@W_up[b]) -> R0
    k_gemm<EPI_ADD,128,64><<<dim3(mt), dim3(256), 0, stream>>>(aggA, WT + OFF_UP + b*8192, nullptr, nullptr, nullptr, R0, nullptr, nullptr, E);
    // h = silu(x@W_ji[b]+b_ji) + t1 -> R1
    k_gemm<EPI_ADD,128,128><<<dim3(mt), dim3(256), 0, stream>>>(XB, WT + OFF_JI + b*16384, bji + b*128, R0, nullptr, R1, nullptr, nullptr, E);
    // t = silu(h@W_bs1+b) -> R0
    k_gemm<EPI_ADD,128,128><<<dim3(mt), dim3(256), 0, stream>>>(R1, WT + OFF_BS1 + b*16384, bbs1 + b*128, nullptr, nullptr, R0, nullptr, nullptr, E);
    // h = h + silu(t@W_bs2+b) -> R1 (aux = R1 in-place)
    k_gemm<EPI_ADD,128,128><<<dim3(mt), dim3(256), 0, stream>>>(R0, WT + OFF_BS2 + b*16384, bbs2 + b*128, R1, nullptr, R1, nullptr, nullptr, E);
    // h2 = silu(h@W_lin+b) + x -> R0
    k_gemm<EPI_ADD,128,128><<<dim3(mt), dim3(256), 0, stream>>>(R1, WT + OFF_LIN + b*16384, blin + b*128, XB, nullptr, R0, nullptr, nullptr, E);
    // t2 = silu(h2@W_as1+b) -> R1
    k_gemm<EPI_ADD,128,128><<<dim3(mt), dim3(256), 0, stream>>>(R0, WT + OFF_AS1 + b*16384, bas1 + b*128, nullptr, nullptr, R1, nullptr, nullptr, E);
    // h_out = h2 + silu(t2@W_as2+b); accumulate or finalize
    if (c < 6)
      k_gemm<EPI_ACC,128,128><<<dim3(mt), dim3(256), 0, stream>>>(R1, WT + OFF_AS2 + b*16384, bas2 + b*128, R0, ACC, nullptr, nullptr, alphaP, E);
    else
      k_gemm<EPI_FIN,128,128><<<dim3(mt), dim3(256), 0, stream>>>(R1, WT + OFF_AS2 + b*16384, bas2 + b*128, R0, ACC, nullptr, (float*)d_out, alphaP, E);
  }
  (void)n_in; (void)out_size;
}

// Round 3
// 3102.194 us; speedup vs baseline: 1.0343x; 1.0343x over previous
//
#include <hip/hip_runtime.h>
#include <stdint.h>

typedef unsigned short u16;
typedef __attribute__((ext_vector_type(8))) short bfrag;   // 8 bf16 = 4 VGPR MFMA operand
typedef __attribute__((ext_vector_type(4))) float f32x4;   // MFMA accumulator

#define DEVI __device__ __forceinline__

DEVI float b2f(u16 u){ return __uint_as_float(((uint32_t)u) << 16); }
DEVI u16 f2b(float f){
  uint32_t x = __float_as_uint(f);
  uint32_t r = (x + 0x7fffu + ((x >> 16) & 1u)) >> 16;   // RNE
  return (u16)r;
}
DEVI float silu_f(float v){ return v / (1.0f + __expf(-v)); }

// ---- transposed-weight arena element offsets (bf16 elements) ----
#define OFF_KJ   0
#define OFF_DOWN 16384
#define OFF_JI   24576
#define OFF_UP   122880
#define OFF_BS1  172032
#define OFF_BS2  270336
#define OFF_LIN  368640
#define OFF_AS1  466944
#define OFF_AS2  565248
#define WT_TOTAL 663552

struct TW {
  const float *kj, *down, *ji, *up, *bs1, *bs2, *lin, *as1, *as2;
  u16* dst;
};

// Transpose+convert all weight matrices fp32 [K,N] -> bf16 [N,K] once.
__global__ void __launch_bounds__(256) k_transpose(TW p){
  int id = blockIdx.y;
  const float* src; int K, N; int doff;
  if      (id == 0) { src = p.kj;                K = 128; N = 128; doff = OFF_KJ; }
  else if (id == 1) { src = p.down;              K = 128; N = 64;  doff = OFF_DOWN; }
  else if (id < 8)  { int b = id - 2;  src = p.ji  + b*16384; K = 128; N = 128; doff = OFF_JI  + b*16384; }
  else if (id < 14) { int b = id - 8;  src = p.up  + b*8192;  K = 64;  N = 128; doff = OFF_UP  + b*8192;  }
  else if (id < 20) { int b = id - 14; src = p.bs1 + b*16384; K = 128; N = 128; doff = OFF_BS1 + b*16384; }
  else if (id < 26) { int b = id - 20; src = p.bs2 + b*16384; K = 128; N = 128; doff = OFF_BS2 + b*16384; }
  else if (id < 32) { int b = id - 26; src = p.lin + b*16384; K = 128; N = 128; doff = OFF_LIN + b*16384; }
  else if (id < 38) { int b = id - 32; src = p.as1 + b*16384; K = 128; N = 128; doff = OFF_AS1 + b*16384; }
  else              { int b = id - 38; src = p.as2 + b*16384; K = 128; N = 128; doff = OFF_AS2 + b*16384; }
  int idx = blockIdx.x*256 + threadIdx.x;
  if (idx >= K*N) return;
  int n = idx / K, k = idx - n*K;
  p.dst[doff + idx] = f2b(src[k*N + n]);
}

// elementwise fp32 -> bf16
__global__ void __launch_bounds__(256) k_f2b(
    const float* __restrict__ src, u16* __restrict__ dst, int n)
{
  int i = blockIdx.x*256 + threadIdx.x;
  if (i < n) dst[i] = f2b(src[i]);
}

// rbf2[e,h] = ((rbf @ W_rbf1) @ W_rbf2)[e,h]  (fp32 in, bf16 out)
__global__ void __launch_bounds__(256) k_rbf(
    const float* __restrict__ rbf, const float* __restrict__ W1,
    const float* __restrict__ W2, u16* __restrict__ out, int E)
{
  __shared__ float w1s[48];
  __shared__ float w2s[1024];
  for (int i = threadIdx.x; i < 48;   i += 256) w1s[i] = W1[i];
  for (int i = threadIdx.x; i < 1024; i += 256) w2s[i] = W2[i];
  __syncthreads();
  int idx = blockIdx.x*256 + threadIdx.x;
  if (idx >= E*128) return;
  int e = idx >> 7, h = idx & 127;
  float rv[6];
#pragma unroll
  for (int k = 0; k < 6; k++) rv[k] = rbf[e*6 + k];
  float o = 0.f;
#pragma unroll
  for (int j = 0; j < 8; j++){
    float m = 0.f;
#pragma unroll
    for (int k = 0; k < 6; k++) m += rv[k] * w1s[k*8 + j];
    o += m * w2s[j*128 + h];
  }
  out[idx] = f2b(o);
}

// s1[t,0:8] = (sbf @ W_sbf1)[t]  (fp32 in, fp32 out)
__global__ void __launch_bounds__(256) k_s1(
    const float* __restrict__ sbf, const float* __restrict__ W1,
    float* __restrict__ s1, int T)
{
  __shared__ float w1s[336];
  for (int i = threadIdx.x; i < 336; i += 256) w1s[i] = W1[i];
  __syncthreads();
  int t = blockIdx.x*256 + threadIdx.x;
  if (t >= T) return;
  const float* row = sbf + (size_t)t*42;
  float a[8];
#pragma unroll
  for (int j = 0; j < 8; j++) a[j] = 0.f;
  for (int k = 0; k < 42; k++){
    float sv = row[k];
#pragma unroll
    for (int j = 0; j < 8; j++) a[j] += sv * w1s[k*8 + j];
  }
#pragma unroll
  for (int j = 0; j < 8; j++) s1[(size_t)t*8 + j] = a[j];
}

// one wave per triplet: sbf_e = s1 @ W_sbf2; v = x_kj[idx_kj]*sbf_e; scatter into agg[branch]
__global__ void __launch_bounds__(256) k_triplet(
    const int* __restrict__ idx_kj, const int* __restrict__ idx_ji,
    const int* __restrict__ bt, const float* __restrict__ s1,
    const float* __restrict__ Wsbf2, const u16* __restrict__ xkj,
    float* __restrict__ agg, int T, int E)
{
  int g = blockIdx.x*256 + threadIdx.x;
  int t = g >> 6, lane = g & 63;
  if (t >= T) return;
  int kj = idx_kj[t], ji = idx_ji[t];
  int b = bt[kj] + 1;
  b = b < 0 ? 0 : (b > 5 ? 5 : b);
  float se = 0.f;
#pragma unroll
  for (int j = 0; j < 8; j++) se += s1[(size_t)t*8 + j] * Wsbf2[j*64 + lane];
  float v = b2f(xkj[(size_t)kj*64 + lane]) * se;
  unsafeAtomicAdd(&agg[((size_t)b*E + ji)*64 + lane], v);
}

// agg fp32 -> aggb bf16 slots 0..5, slot 6 = sum (== agg_gen)
__global__ void __launch_bounds__(256) k_cvt(
    const float* __restrict__ agg, u16* __restrict__ aggb, int EI)
{
  int idx = blockIdx.x*256 + threadIdx.x;
  if (idx >= EI) return;
  float s = 0.f;
#pragma unroll
  for (int b = 0; b < 6; b++){
    float v = agg[(size_t)b*EI + idx];
    s += v;
    aggb[(size_t)b*EI + idx] = f2b(v);
  }
  aggb[(size_t)6*EI + idx] = f2b(s);
}

// d_out[i] = alpha*h6[i] + (1-alpha)*sum_{c<6} hc[i]   (vectorized x4)
__global__ void __launch_bounds__(256) k_reduce(
    const u16* __restrict__ O7, const float* __restrict__ alphaP,
    float* __restrict__ out, int EH)
{
  int i4 = blockIdx.x*256 + threadIdx.x;
  size_t base = (size_t)i4*4;
  if (base >= (size_t)EH) return;
  float al = alphaP[0];
  float s0=0,s1=0,s2=0,s3=0;
#pragma unroll
  for (int c = 0; c < 6; c++){
    ushort4 v = *(const ushort4*)&O7[(size_t)c*EH + base];
    s0 += b2f(v.x); s1 += b2f(v.y); s2 += b2f(v.z); s3 += b2f(v.w);
  }
  ushort4 g = *(const ushort4*)&O7[(size_t)6*EH + base];
  float4 o;
  o.x = al*b2f(g.x) + (1.f-al)*s0;
  o.y = al*b2f(g.y) + (1.f-al)*s1;
  o.z = al*b2f(g.z) + (1.f-al)*s2;
  o.w = al*b2f(g.w) + (1.f-al)*s3;
  *(float4*)&out[base] = o;
}

// ================== batched fused-epilogue MFMA GEMM ==================
// grid (mt, NC). Slice c: A+c*aStr [M,K] @ W[min(c,5)] [K,N] -> out+c*oStr.
// MODE 0: out = silu(AW+bias) * aux;  MODE 1: out = silu(AW+bias) (+ aux)
// Epilogue goes through LDS for vectorized (8B) aux loads & stores.
template<int MODE, int N, int K>
__global__ void __launch_bounds__(256) k_gemmb(
    const u16* __restrict__ A, size_t aStr,
    const u16* __restrict__ WTp, int wStr,
    const float* __restrict__ bias, int bStr,
    const u16* __restrict__ aux, size_t xStr,
    u16* __restrict__ out, size_t oStr,
    int M)
{
  constexpr int KP = K + 8;                  // bf16 pad: 2-way aliasing (free)
  constexpr int PITCH = N + 4;               // f32 epilogue pitch
  constexpr size_t SW = (size_t)KP*N*2;
  constexpr size_t SE = (size_t)64*PITCH*4;  // 64 rows per epilogue pass
  constexpr size_t SMEM = SW > SE ? SW : SE;
  __shared__ __attribute__((aligned(16))) char smem[SMEM];
  u16*   wlds = (u16*)smem;
  float* elds = (float*)smem;

  const int tid = threadIdx.x;
  const int c = blockIdx.y;
  const int wsel = c < 5 ? c : 5;
  const u16* __restrict__ Ac = A + (size_t)c*aStr;
  const u16* __restrict__ Wc = WTp + (size_t)wsel*wStr;
  const u16* __restrict__ auxc = aux ? aux + (size_t)c*xStr : (const u16*)0;
  u16* __restrict__ outc = out + (size_t)c*oStr;

  // stage weights [N,K] bf16 -> LDS
  constexpr int CH = (N*K)/8;
  for (int ch = tid; ch < CH; ch += 256){
    int n  = ch / (K/8);
    int kc = (ch - n*(K/8))*8;
    *(int4*)&wlds[n*KP + kc] = *(const int4*)&Wc[n*K + kc];
  }
  __syncthreads();

  const int wave = tid >> 6, lane = tid & 63;
  const int lr = lane & 15, lq = lane >> 4;
  const int m0 = blockIdx.x*128 + wave*32;
  constexpr int NBN = N/16;
  f32x4 acc[2][NBN];
#pragma unroll
  for (int i = 0; i < 2; i++)
#pragma unroll
    for (int j = 0; j < NBN; j++) acc[i][j] = (f32x4){0.f,0.f,0.f,0.f};

  const int r0 = m0 + lr;
#pragma unroll
  for (int ks = 0; ks < K/32; ks++){
    const int k0 = ks*32 + lq*8;
    bfrag a0 = {0,0,0,0,0,0,0,0}, a1 = {0,0,0,0,0,0,0,0};
    if (r0 < M)      a0 = *(const bfrag*)&Ac[(size_t)r0*K + k0];
    if (r0 + 16 < M) a1 = *(const bfrag*)&Ac[(size_t)(r0+16)*K + k0];
#pragma unroll
    for (int nb = 0; nb < NBN; nb++){
      bfrag bv = *(const bfrag*)&wlds[(nb*16 + lr)*KP + k0];
      acc[0][nb] = __builtin_amdgcn_mfma_f32_16x16x32_bf16(a0, bv, acc[0][nb], 0, 0, 0);
      acc[1][nb] = __builtin_amdgcn_mfma_f32_16x16x32_bf16(a1, bv, acc[1][nb], 0, 0, 0);
    }
  }

  // per-lane bias for its cols (col = nb*16+lr)
  float bv[NBN];
#pragma unroll
  for (int nb = 0; nb < NBN; nb++)
    bv[nb] = bias ? bias[wsel*bStr + nb*16 + lr] : 0.f;

  // epilogue: 2 passes of 64 rows (16 rows/wave) through LDS
#pragma unroll
  for (int mb = 0; mb < 2; mb++){
    __syncthreads();   // weights reads done (mb=0) / prev readout done (mb=1)
#pragma unroll
    for (int nb = 0; nb < NBN; nb++){
      const int col = nb*16 + lr;
#pragma unroll
      for (int r = 0; r < 4; r++){
        float v = silu_f(acc[mb][nb][r] + bv[nb]);
        elds[(wave*16 + lq*4 + r)*PITCH + col] = v;
      }
    }
    __syncthreads();
    constexpr int CHUNKS = 64*N/4;
    for (int q = tid; q < CHUNKS; q += 256){
      int lrow = q / (N/4);
      int col0 = (q - lrow*(N/4))*4;
      int w = lrow >> 4, rr = lrow & 15;
      int grow = blockIdx.x*128 + w*32 + mb*16 + rr;
      if (grow >= M) continue;
      float4 v = *(float4*)&elds[lrow*PITCH + col0];
      size_t oi = (size_t)grow*N + col0;
      float o0 = v.x, o1 = v.y, o2 = v.z, o3 = v.w;
      if (MODE == 0){
        ushort4 av = *(const ushort4*)&auxc[oi];
        o0 *= b2f(av.x); o1 *= b2f(av.y); o2 *= b2f(av.z); o3 *= b2f(av.w);
      } else if (auxc){
        ushort4 av = *(const ushort4*)&auxc[oi];
        o0 += b2f(av.x); o1 += b2f(av.y); o2 += b2f(av.z); o3 += b2f(av.w);
      }
      ushort4 ov; ov.x = f2b(o0); ov.y = f2b(o1); ov.z = f2b(o2); ov.w = f2b(o3);
      *(ushort4*)&outc[oi] = ov;
    }
  }
}

// ================== legacy (round-2, verified) serial GEMM ==================
enum { EPI_MUL = 0, EPI_ADD = 1, EPI_ACC = 2, EPI_FIN = 3 };

template<int MODE, int N, int K>
__global__ void __launch_bounds__(256) k_gemm(
    const u16* __restrict__ A, const u16* __restrict__ WT,
    const float* __restrict__ bias, const u16* __restrict__ aux,
    float* __restrict__ accF, u16* __restrict__ outB,
    float* __restrict__ outF, const float* __restrict__ alphaPtr, int M)
{
  constexpr int KP = K + 8;
  __shared__ __attribute__((aligned(16))) u16 lds[KP*N];
  const int tid = threadIdx.x;
  constexpr int CH = (N*K)/8;
  for (int ch = tid; ch < CH; ch += 256){
    int n  = ch / (K/8);
    int kc = (ch - n*(K/8))*8;
    *(int4*)&lds[n*KP + kc] = *(const int4*)&WT[n*K + kc];
  }
  __syncthreads();

  const int wave = tid >> 6, lane = tid & 63;
  const int lr = lane & 15, lq = lane >> 4;
  const int m0 = blockIdx.x*128 + wave*32;
  constexpr int NBN = N/16;
  f32x4 acc[2][NBN];
#pragma unroll
  for (int i = 0; i < 2; i++)
#pragma unroll
    for (int j = 0; j < NBN; j++) acc[i][j] = (f32x4){0.f,0.f,0.f,0.f};

  const int r0 = m0 + lr;
#pragma unroll
  for (int ks = 0; ks < K/32; ks++){
    const int k0 = ks*32 + lq*8;
    bfrag a0 = {0,0,0,0,0,0,0,0}, a1 = {0,0,0,0,0,0,0,0};
    if (r0 < M)      a0 = *(const bfrag*)&A[(size_t)r0*K + k0];
    if (r0 + 16 < M) a1 = *(const bfrag*)&A[(size_t)(r0+16)*K + k0];
#pragma unroll
    for (int nb = 0; nb < NBN; nb++){
      bfrag bv = *(const bfrag*)&lds[(nb*16 + lr)*KP + k0];
      acc[0][nb] = __builtin_amdgcn_mfma_f32_16x16x32_bf16(a0, bv, acc[0][nb], 0, 0, 0);
      acc[1][nb] = __builtin_amdgcn_mfma_f32_16x16x32_bf16(a1, bv, acc[1][nb], 0, 0, 0);
    }
  }

  float sc = 0.f;
  if (MODE == EPI_ACC || MODE == EPI_FIN){
    float al = alphaPtr[0];
    sc = (MODE == EPI_FIN) ? al : (1.0f - al);
  }

#pragma unroll
  for (int mb = 0; mb < 2; mb++){
    const int rowb = m0 + mb*16 + lq*4;
#pragma unroll
    for (int nb = 0; nb < NBN; nb++){
      const int col = nb*16 + lr;
      const float bvv = bias ? bias[col] : 0.f;
#pragma unroll
      for (int r = 0; r < 4; r++){
        const int row = rowb + r;
        if (row >= M) continue;
        const size_t oi = (size_t)row*N + col;
        float v = silu_f(acc[mb][nb][r] + bvv);
        if (MODE == EPI_MUL){
          v *= b2f(aux[oi]);
          outB[oi] = f2b(v);
        } else if (MODE == EPI_ADD){
          if (aux) v += b2f(aux[oi]);
          outB[oi] = f2b(v);
        } else if (MODE == EPI_ACC){
          v += b2f(aux[oi]);
          accF[oi] += sc*v;
        } else {
          v += b2f(aux[oi]);
          outF[oi] = sc*v + accF[oi];
        }
      }
    }
  }
}

extern "C" void kernel_launch(void* const* d_in, const int* in_sizes, int n_in,
                              void* d_out, int out_size, void* d_ws, size_t ws_size,
                              hipStream_t stream)
{
  const float* x     = (const float*)d_in[0];
  const float* rbf   = (const float*)d_in[1];
  const float* sbf   = (const float*)d_in[2];
  const int*   ikj   = (const int*)d_in[3];
  const int*   iji   = (const int*)d_in[4];
  const int*   bt    = (const int*)d_in[5];
  const float* alphaP= (const float*)d_in[6];
  const float* Wrbf1 = (const float*)d_in[8];
  const float* Wrbf2 = (const float*)d_in[9];
  const float* Wsbf1 = (const float*)d_in[10];
  const float* Wsbf2 = (const float*)d_in[11];
  const float* Wkj   = (const float*)d_in[12];
  const float* bkj   = (const float*)d_in[13];
  const float* Wji   = (const float*)d_in[14];
  const float* bji   = (const float*)d_in[15];
  const float* Wdown = (const float*)d_in[16];
  const float* Wup   = (const float*)d_in[17];
  const float* Wbs1  = (const float*)d_in[18];
  const float* bbs1  = (const float*)d_in[19];
  const float* Wbs2  = (const float*)d_in[20];
  const float* bbs2  = (const float*)d_in[21];
  const float* Wlin  = (const float*)d_in[22];
  const float* blin  = (const float*)d_in[23];
  const float* Was1  = (const float*)d_in[24];
  const float* bas1  = (const float*)d_in[25];
  const float* Was2  = (const float*)d_in[26];
  const float* bas2  = (const float*)d_in[27];

  const int E = in_sizes[5];
  const int T = in_sizes[3];
  const int H = 128, I = 64;
  const size_t EH = (size_t)E*H, EI = (size_t)E*I;
  const int mt = (E + 127)/128;

  TW tw{Wkj, Wdown, Wji, Wup, Wbs1, Wbs2, Wlin, Was1, Was2, (u16*)0};

  // ---------- batched arena ----------
  {
    char* ws = (char*)d_ws;
    size_t off = 0;
    auto arena = [&](size_t bytes)->size_t{
      size_t o = off; off += (bytes + 255) & ~(size_t)255; return o;
    };
    size_t oWT   = arena((size_t)WT_TOTAL*2);           // 1.33 MB
    size_t oXB   = arena(EH*2);                         // 25.6 MB
    size_t oXKJ  = arena(EI*2);                         // 12.8 MB
    size_t oBufA = arena(7*EH*2);                       // 179.2 MB
    size_t big   = 6*EI*4 + 7*EI*2;                     // AGG + AGGB = 243.2 MB
    size_t oBufB = arena(big > 7*EH*2 ? big : 7*EH*2);
    size_t oOUT7 = arena(7*EH*2);                       // 179.2 MB

    if (off <= ws_size){
      u16*   WTb  = (u16*)(ws + oWT);
      u16*   XB   = (u16*)(ws + oXB);
      u16*   XKJ  = (u16*)(ws + oXKJ);
      u16*   BufA = (u16*)(ws + oBufA);
      u16*   BufB = (u16*)(ws + oBufB);
      float* AGG  = (float*)(ws + oBufB);               // alias (pre-chain)
      u16*   AGGB = (u16*)(ws + oBufB + 6*EI*4);        // alias (pre-chain)
      u16*   OUT7 = (u16*)(ws + oOUT7);
      float* S1   = (float*)(BufA + 2*EH);              // 19.2 MB inside BufA
      u16*   RBF2 = BufA;                               // slice 0
      u16*   TMP  = BufA + EH;                          // slice 1

      tw.dst = WTb;
      hipLaunchKernelGGL(k_transpose, dim3(64, 44, 1), dim3(256, 1, 1), 0, stream, tw);
      k_f2b<<<dim3((int)((EH + 255)/256)), dim3(256), 0, stream>>>(x, XB, (int)EH);
      k_rbf<<<dim3((int)((EH + 255)/256)), dim3(256), 0, stream>>>(rbf, Wrbf1, Wrbf2, RBF2, E);
      // t = silu(x@W_kj+b)*rbf2 -> TMP
      k_gemmb<0,128,128><<<dim3(mt,1), dim3(256), 0, stream>>>(XB,0, WTb+OFF_KJ,0, bkj,0, RBF2,0, TMP,0, E);
      // x_kj = silu(t@W_down) -> XKJ
      k_gemmb<1,64,128><<<dim3(mt,1), dim3(256), 0, stream>>>(TMP,0, WTb+OFF_DOWN,0, (const float*)0,0, (const u16*)0,0, XKJ,0, E);
      k_s1<<<dim3((T + 255)/256), dim3(256), 0, stream>>>(sbf, Wsbf1, S1, T);
      hipMemsetAsync(ws + oBufB, 0, 6*EI*4, stream);
      k_triplet<<<dim3((int)(((size_t)T*64 + 255)/256)), dim3(256), 0, stream>>>(ikj, iji, bt, S1, Wsbf2, XKJ, AGG, T, E);
      k_cvt<<<dim3((int)((EI + 255)/256)), dim3(256), 0, stream>>>(AGG, AGGB, (int)EI);

      // batched chain, 7 slices (c=6 uses weights b=5 + agg slot 6 = generic)
      // U:   t1 = silu(agg_c @ W_up[b])                -> BufA
      k_gemmb<1,128,64><<<dim3(mt,7), dim3(256), 0, stream>>>(AGGB,EI, WTb+OFF_UP,8192, (const float*)0,0, (const u16*)0,0, BufA,EH, E);
      // JI:  h = silu(x@W_ji[b]+b) + t1                -> BufB
      k_gemmb<1,128,128><<<dim3(mt,7), dim3(256), 0, stream>>>(XB,0, WTb+OFF_JI,16384, bji,128, BufA,EH, BufB,EH, E);
      // BS1: t = silu(h@W_bs1[b]+b)                    -> BufA
      k_gemmb<1,128,128><<<dim3(mt,7), dim3(256), 0, stream>>>(BufB,EH, WTb+OFF_BS1,16384, bbs1,128, (const u16*)0,0, BufA,EH, E);
      // BS2: h = h + silu(t@W_bs2[b]+b)                -> BufB (in-place aux)
      k_gemmb<1,128,128><<<dim3(mt,7), dim3(256), 0, stream>>>(BufA,EH, WTb+OFF_BS2,16384, bbs2,128, BufB,EH, BufB,EH, E);
      // LIN: h2 = silu(h@W_lin[b]+b) + x               -> BufA
      k_gemmb<1,128,128><<<dim3(mt,7), dim3(256), 0, stream>>>(BufB,EH, WTb+OFF_LIN,16384, blin,128, XB,0, BufA,EH, E);
      // AS1: t2 = silu(h2@W_as1[b]+b)                  -> BufB
      k_gemmb<1,128,128><<<dim3(mt,7), dim3(256), 0, stream>>>(BufA,EH, WTb+OFF_AS1,16384, bas1,128, (const u16*)0,0, BufB,EH, E);
      // AS2: out_c = h2 + silu(t2@W_as2[b]+b)          -> OUT7
      k_gemmb<1,128,128><<<dim3(mt,7), dim3(256), 0, stream>>>(BufB,EH, WTb+OFF_AS2,16384, bas2,128, BufA,EH, OUT7,EH, E);
      // d_out = alpha*out6 + (1-alpha)*sum(out0..5)
      k_reduce<<<dim3((int)((EH/4 + 255)/256)), dim3(256), 0, stream>>>(OUT7, alphaP, (float*)d_out, (int)EH);
      (void)n_in; (void)out_size;
      return;
    }
  }

  // ---------- legacy fallback (round-2 verified path) ----------
  {
    char* ws = (char*)d_ws;
    size_t off = 0;
    auto arena = [&](size_t bytes)->size_t{
      size_t o = off; off += (bytes + 255) & ~(size_t)255; return o;
    };
    size_t oWT   = arena((size_t)WT_TOTAL*2);
    size_t oXB   = arena(EH*2);
    size_t oR0   = arena(EH*2);
    size_t oR1   = arena(EH*2);
    size_t oXKJ  = arena(EI*2);
    size_t oAGG  = arena(6*EI*4);
    size_t oAGGB = arena(7*EI*2);
    if (off > ws_size) return;

    u16*   WTb  = (u16*)(ws + oWT);
    u16*   XB   = (u16*)(ws + oXB);
    u16*   R0   = (u16*)(ws + oR0);
    u16*   R1   = (u16*)(ws + oR1);
    u16*   XKJ  = (u16*)(ws + oXKJ);
    float* AGG  = (float*)(ws + oAGG);
    u16*   AGGB = (u16*)(ws + oAGGB);
    float* ACC  = (float*)(ws + oAGG);
    float* S1   = (float*)(ws + oR0);

    tw.dst = WTb;
    hipLaunchKernelGGL(k_transpose, dim3(64, 44, 1), dim3(256, 1, 1), 0, stream, tw);
    k_f2b<<<dim3((int)((EH + 255)/256)), dim3(256), 0, stream>>>(x, XB, (int)EH);
    k_rbf<<<dim3((int)((EH + 255)/256)), dim3(256), 0, stream>>>(rbf, Wrbf1, Wrbf2, R0, E);
    k_gemm<EPI_MUL,128,128><<<dim3(mt), dim3(256), 0, stream>>>(XB, WTb + OFF_KJ, bkj, R0, nullptr, R1, nullptr, nullptr, E);
    k_gemm<EPI_ADD,64,128><<<dim3(mt), dim3(256), 0, stream>>>(R1, WTb + OFF_DOWN, nullptr, nullptr, nullptr, XKJ, nullptr, nullptr, E);
    k_s1<<<dim3((T + 255)/256), dim3(256), 0, stream>>>(sbf, Wsbf1, S1, T);
    hipMemsetAsync(ws + oAGG, 0, 6*EI*4, stream);
    k_triplet<<<dim3((int)(((size_t)T*64 + 255)/256)), dim3(256), 0, stream>>>(ikj, iji, bt, S1, Wsbf2, XKJ, AGG, T, E);
    k_cvt<<<dim3((int)((EI + 255)/256)), dim3(256), 0, stream>>>(AGG, AGGB, (int)EI);
    hipMemsetAsync(ws + oAGG, 0, EH*4, stream);

    for (int c = 0; c < 7; c++){
      const int b    = (c < 6) ? c : 5;
      const int slot = (c < 6) ? c : 6;
      const u16* aggA = AGGB + (size_t)slot*EI;
      k_gemm<EPI_ADD,128,64><<<dim3(mt), dim3(256), 0, stream>>>(aggA, WTb + OFF_UP + b*8192, nullptr, nullptr, nullptr, R0, nullptr, nullptr, E);
      k_gemm<EPI_ADD,128,128><<<dim3(mt), dim3(256), 0, stream>>>(XB, WTb + OFF_JI + b*16384, bji + b*128, R0, nullptr, R1, nullptr, nullptr, E);
      k_gemm<EPI_ADD,128,128><<<dim3(mt), dim3(256), 0, stream>>>(R1, WTb + OFF_BS1 + b*16384, bbs1 + b*128, nullptr, nullptr, R0, nullptr, nullptr, E);
      k_gemm<EPI_ADD,128,128><<<dim3(mt), dim3(256), 0, stream>>>(R0, WTb + OFF_BS2 + b*16384, bbs2 + b*128, R1, nullptr, R1, nullptr, nullptr, E);
      k_gemm<EPI_ADD,128,128><<<dim3(mt), dim3(256), 0, stream>>>(R1, WTb + OFF_LIN + b*16384, blin + b*128, XB, nullptr, R0, nullptr, nullptr, E);
      k_gemm<EPI_ADD,128,128><<<dim3(mt), dim3(256), 0, stream>>>(R0, WTb + OFF_AS1 + b*16384, bas1 + b*128, nullptr, nullptr, R1, nullptr, nullptr, E);
      if (c < 6)
        k_gemm<EPI_ACC,128,128><<<dim3(mt), dim3(256), 0, stream>>>(R1, WTb + OFF_AS2 + b*16384, bas2 + b*128, R0, ACC, nullptr, nullptr, alphaP, E);
      else
        k_gemm<EPI_FIN,128,128><<<dim3(mt), dim3(256), 0, stream>>>(R1, WTb + OFF_AS2 + b*16384, bas2 + b*128, R0, ACC, nullptr, (float*)d_out, alphaP, E);
    }
  }
  (void)n_in; (void)out_size;
}

// Round 4
// 1507.946 us; speedup vs baseline: 2.1279x; 2.0572x over previous
//
#include <hip/hip_runtime.h>
#include <stdint.h>

typedef unsigned short u16;
typedef __attribute__((ext_vector_type(8))) short bfrag;   // 8 bf16 = 4 VGPR MFMA operand
typedef __attribute__((ext_vector_type(4))) float f32x4;   // MFMA accumulator

#define DEVI __device__ __forceinline__

DEVI float b2f(u16 u){ return __uint_as_float(((uint32_t)u) << 16); }
DEVI u16 f2b(float f){
  uint32_t x = __float_as_uint(f);
  uint32_t r = (x + 0x7fffu + ((x >> 16) & 1u)) >> 16;   // RNE
  return (u16)r;
}
DEVI float silu_f(float v){ return v / (1.0f + __expf(-v)); }

// ---- transposed-weight arena element offsets (bf16 elements) ----
#define OFF_KJ   0
#define OFF_DOWN 16384
#define OFF_JI   24576
#define OFF_UP   122880
#define OFF_BS1  172032
#define OFF_BS2  270336
#define OFF_LIN  368640
#define OFF_AS1  466944
#define OFF_AS2  565248
#define WT_TOTAL 663552

struct TW {
  const float *kj, *down, *ji, *up, *bs1, *bs2, *lin, *as1, *as2;
  u16* dst;
};

// Transpose+convert all weight matrices fp32 [K,N] -> bf16 [N,K] once.
__global__ void __launch_bounds__(256) k_transpose(TW p){
  int id = blockIdx.y;
  const float* src; int K, N; int doff;
  if      (id == 0) { src = p.kj;                K = 128; N = 128; doff = OFF_KJ; }
  else if (id == 1) { src = p.down;              K = 128; N = 64;  doff = OFF_DOWN; }
  else if (id < 8)  { int b = id - 2;  src = p.ji  + b*16384; K = 128; N = 128; doff = OFF_JI  + b*16384; }
  else if (id < 14) { int b = id - 8;  src = p.up  + b*8192;  K = 64;  N = 128; doff = OFF_UP  + b*8192;  }
  else if (id < 20) { int b = id - 14; src = p.bs1 + b*16384; K = 128; N = 128; doff = OFF_BS1 + b*16384; }
  else if (id < 26) { int b = id - 20; src = p.bs2 + b*16384; K = 128; N = 128; doff = OFF_BS2 + b*16384; }
  else if (id < 32) { int b = id - 26; src = p.lin + b*16384; K = 128; N = 128; doff = OFF_LIN + b*16384; }
  else if (id < 38) { int b = id - 32; src = p.as1 + b*16384; K = 128; N = 128; doff = OFF_AS1 + b*16384; }
  else              { int b = id - 38; src = p.as2 + b*16384; K = 128; N = 128; doff = OFF_AS2 + b*16384; }
  int idx = blockIdx.x*256 + threadIdx.x;
  if (idx >= K*N) return;
  int n = idx / K, k = idx - n*K;
  p.dst[doff + idx] = f2b(src[k*N + n]);
}

// elementwise fp32 -> bf16
__global__ void __launch_bounds__(256) k_f2b(
    const float* __restrict__ src, u16* __restrict__ dst, int n)
{
  int i = blockIdx.x*256 + threadIdx.x;
  if (i < n) dst[i] = f2b(src[i]);
}

// rbf2[e,h] = ((rbf @ W_rbf1) @ W_rbf2)[e,h]  (fp32 in, bf16 out)
__global__ void __launch_bounds__(256) k_rbf(
    const float* __restrict__ rbf, const float* __restrict__ W1,
    const float* __restrict__ W2, u16* __restrict__ out, int E)
{
  __shared__ float w1s[48];
  __shared__ float w2s[1024];
  for (int i = threadIdx.x; i < 48;   i += 256) w1s[i] = W1[i];
  for (int i = threadIdx.x; i < 1024; i += 256) w2s[i] = W2[i];
  __syncthreads();
  int idx = blockIdx.x*256 + threadIdx.x;
  if (idx >= E*128) return;
  int e = idx >> 7, h = idx & 127;
  float rv[6];
#pragma unroll
  for (int k = 0; k < 6; k++) rv[k] = rbf[e*6 + k];
  float o = 0.f;
#pragma unroll
  for (int j = 0; j < 8; j++){
    float m = 0.f;
#pragma unroll
    for (int k = 0; k < 6; k++) m += rv[k] * w1s[k*8 + j];
    o += m * w2s[j*128 + h];
  }
  out[idx] = f2b(o);
}

// s1[t,0:8] = (sbf @ W_sbf1)[t]  (fp32 in, fp32 out)
__global__ void __launch_bounds__(256) k_s1(
    const float* __restrict__ sbf, const float* __restrict__ W1,
    float* __restrict__ s1, int T)
{
  __shared__ float w1s[336];
  for (int i = threadIdx.x; i < 336; i += 256) w1s[i] = W1[i];
  __syncthreads();
  int t = blockIdx.x*256 + threadIdx.x;
  if (t >= T) return;
  const float* row = sbf + (size_t)t*42;
  float a[8];
#pragma unroll
  for (int j = 0; j < 8; j++) a[j] = 0.f;
  for (int k = 0; k < 42; k++){
    float sv = row[k];
#pragma unroll
    for (int j = 0; j < 8; j++) a[j] += sv * w1s[k*8 + j];
  }
#pragma unroll
  for (int j = 0; j < 8; j++) s1[(size_t)t*8 + j] = a[j];
}

// one wave per triplet: sbf_e = s1 @ W_sbf2; v = x_kj[idx_kj]*sbf_e; scatter into agg[branch]
__global__ void __launch_bounds__(256) k_triplet(
    const int* __restrict__ idx_kj, const int* __restrict__ idx_ji,
    const int* __restrict__ bt, const float* __restrict__ s1,
    const float* __restrict__ Wsbf2, const u16* __restrict__ xkj,
    float* __restrict__ agg, int T, int E)
{
  int g = blockIdx.x*256 + threadIdx.x;
  int t = g >> 6, lane = g & 63;
  if (t >= T) return;
  int kj = idx_kj[t], ji = idx_ji[t];
  int b = bt[kj] + 1;
  b = b < 0 ? 0 : (b > 5 ? 5 : b);
  float se = 0.f;
#pragma unroll
  for (int j = 0; j < 8; j++) se += s1[(size_t)t*8 + j] * Wsbf2[j*64 + lane];
  float v = b2f(xkj[(size_t)kj*64 + lane]) * se;
  unsafeAtomicAdd(&agg[((size_t)b*E + ji)*64 + lane], v);
}

// agg fp32 -> aggb bf16 slots 0..5, slot 6 = sum (== agg_gen)
__global__ void __launch_bounds__(256) k_cvt(
    const float* __restrict__ agg, u16* __restrict__ aggb, int EI)
{
  int idx = blockIdx.x*256 + threadIdx.x;
  if (idx >= EI) return;
  float s = 0.f;
#pragma unroll
  for (int b = 0; b < 6; b++){
    float v = agg[(size_t)b*EI + idx];
    s += v;
    aggb[(size_t)b*EI + idx] = f2b(v);
  }
  aggb[(size_t)6*EI + idx] = f2b(s);
}

// reduce nsl slices of S into out (fp32): scale = (genLast && last) ? alpha : (1-alpha)
__global__ void __launch_bounds__(256) k_red(
    const u16* __restrict__ S, const float* __restrict__ alphaP,
    float* __restrict__ out, size_t EH, int nsl, int genLast, int accum)
{
  size_t base = ((size_t)blockIdx.x*256 + threadIdx.x)*4;
  if (base >= EH) return;
  float al = alphaP[0];
  float s0=0,s1=0,s2=0,s3=0;
  for (int c = 0; c < nsl; c++){
    float sc = (genLast && c == nsl-1) ? al : (1.f - al);
    ushort4 v = *(const ushort4*)&S[(size_t)c*EH + base];
    s0 += sc*b2f(v.x); s1 += sc*b2f(v.y); s2 += sc*b2f(v.z); s3 += sc*b2f(v.w);
  }
  float4 o;
  if (accum){
    float4 p = *(const float4*)&out[base];
    o.x = p.x + s0; o.y = p.y + s1; o.z = p.z + s2; o.w = p.w + s3;
  } else {
    o.x = s0; o.y = s1; o.z = s2; o.w = s3;
  }
  *(float4*)&out[base] = o;
}

// ================== batched fused-epilogue MFMA GEMM ==================
// grid (mt, nsl). Slice sl=blockIdx.y: A+sl*aStr [M,K] @ W[min(cBase+sl,5)] [K,N]
// -> out+sl*oStr.  MODE 0: out = silu(AW+b)*aux;  MODE 1: out = silu(AW+b)(+aux).
// Epilogue round-trips LDS for vectorized (8B) aux loads & stores. aux==out OK.
template<int MODE, int N, int K>
__global__ void __launch_bounds__(256) k_gemmb(
    const u16* __restrict__ A, size_t aStr,
    const u16* __restrict__ WTp, int wStr,
    const float* __restrict__ bias, int bStr,
    const u16* __restrict__ aux, size_t xStr,
    u16* __restrict__ out, size_t oStr,
    int cBase, int M)
{
  constexpr int KP = K + 8;                  // bf16 pad: 2-way aliasing (free)
  constexpr int PITCH = N + 4;               // f32 epilogue pitch
  constexpr size_t SW = (size_t)KP*N*2;
  constexpr size_t SE = (size_t)64*PITCH*4;  // 64 rows per epilogue pass
  constexpr size_t SMEM = SW > SE ? SW : SE;
  __shared__ __attribute__((aligned(16))) char smem[SMEM];
  u16*   wlds = (u16*)smem;
  float* elds = (float*)smem;

  const int tid = threadIdx.x;
  const int sl = blockIdx.y;
  const int c = cBase + sl;
  const int wsel = c < 5 ? c : 5;
  const u16* __restrict__ Ac = A + (size_t)sl*aStr;
  const u16* __restrict__ Wc = WTp + (size_t)wsel*wStr;
  const u16* __restrict__ auxc = aux ? aux + (size_t)sl*xStr : (const u16*)0;
  u16* __restrict__ outc = out + (size_t)sl*oStr;

  // stage weights [N,K] bf16 -> LDS
  constexpr int CH = (N*K)/8;
  for (int ch = tid; ch < CH; ch += 256){
    int n  = ch / (K/8);
    int kc = (ch - n*(K/8))*8;
    *(int4*)&wlds[n*KP + kc] = *(const int4*)&Wc[n*K + kc];
  }
  __syncthreads();

  const int wave = tid >> 6, lane = tid & 63;
  const int lr = lane & 15, lq = lane >> 4;
  const int m0 = blockIdx.x*128 + wave*32;
  constexpr int NBN = N/16;
  f32x4 acc[2][NBN];
#pragma unroll
  for (int i = 0; i < 2; i++)
#pragma unroll
    for (int j = 0; j < NBN; j++) acc[i][j] = (f32x4){0.f,0.f,0.f,0.f};

  const int r0 = m0 + lr;
#pragma unroll
  for (int ks = 0; ks < K/32; ks++){
    const int k0 = ks*32 + lq*8;
    bfrag a0 = {0,0,0,0,0,0,0,0}, a1 = {0,0,0,0,0,0,0,0};
    if (r0 < M)      a0 = *(const bfrag*)&Ac[(size_t)r0*K + k0];
    if (r0 + 16 < M) a1 = *(const bfrag*)&Ac[(size_t)(r0+16)*K + k0];
#pragma unroll
    for (int nb = 0; nb < NBN; nb++){
      bfrag bv = *(const bfrag*)&wlds[(nb*16 + lr)*KP + k0];
      acc[0][nb] = __builtin_amdgcn_mfma_f32_16x16x32_bf16(a0, bv, acc[0][nb], 0, 0, 0);
      acc[1][nb] = __builtin_amdgcn_mfma_f32_16x16x32_bf16(a1, bv, acc[1][nb], 0, 0, 0);
    }
  }

  // per-lane bias for its cols (col = nb*16+lr)
  float bv[NBN];
#pragma unroll
  for (int nb = 0; nb < NBN; nb++)
    bv[nb] = bias ? bias[wsel*bStr + nb*16 + lr] : 0.f;

  // epilogue: 2 passes of 64 rows through LDS, vectorized readout
#pragma unroll
  for (int mb = 0; mb < 2; mb++){
    __syncthreads();   // weight reads done (mb=0) / prev readout done (mb=1)
#pragma unroll
    for (int nb = 0; nb < NBN; nb++){
      const int col = nb*16 + lr;
#pragma unroll
      for (int r = 0; r < 4; r++){
        float v = silu_f(acc[mb][nb][r] + bv[nb]);
        elds[(wave*16 + lq*4 + r)*PITCH + col] = v;
      }
    }
    __syncthreads();
    constexpr int CHUNKS = 64*N/4;
    for (int q = tid; q < CHUNKS; q += 256){
      int lrow = q / (N/4);
      int col0 = (q - lrow*(N/4))*4;
      int w = lrow >> 4, rr = lrow & 15;
      int grow = blockIdx.x*128 + w*32 + mb*16 + rr;
      if (grow >= M) continue;
      float4 v = *(float4*)&elds[lrow*PITCH + col0];
      size_t oi = (size_t)grow*N + col0;
      float o0 = v.x, o1 = v.y, o2 = v.z, o3 = v.w;
      if (MODE == 0){
        ushort4 av = *(const ushort4*)&auxc[oi];
        o0 *= b2f(av.x); o1 *= b2f(av.y); o2 *= b2f(av.z); o3 *= b2f(av.w);
      } else if (auxc){
        ushort4 av = *(const ushort4*)&auxc[oi];
        o0 += b2f(av.x); o1 += b2f(av.y); o2 += b2f(av.z); o3 += b2f(av.w);
      }
      ushort4 ov; ov.x = f2b(o0); ov.y = f2b(o1); ov.z = f2b(o2); ov.w = f2b(o3);
      *(ushort4*)&outc[oi] = ov;
    }
  }
}

// ================== legacy (verified) serial GEMM ==================
enum { EPI_MUL = 0, EPI_ADD = 1, EPI_ACC = 2, EPI_FIN = 3 };

template<int MODE, int N, int K>
__global__ void __launch_bounds__(256) k_gemm(
    const u16* __restrict__ A, const u16* __restrict__ WT,
    const float* __restrict__ bias, const u16* __restrict__ aux,
    float* __restrict__ accF, u16* __restrict__ outB,
    float* __restrict__ outF, const float* __restrict__ alphaPtr, int M)
{
  constexpr int KP = K + 8;
  __shared__ __attribute__((aligned(16))) u16 lds[KP*N];
  const int tid = threadIdx.x;
  constexpr int CH = (N*K)/8;
  for (int ch = tid; ch < CH; ch += 256){
    int n  = ch / (K/8);
    int kc = (ch - n*(K/8))*8;
    *(int4*)&lds[n*KP + kc] = *(const int4*)&WT[n*K + kc];
  }
  __syncthreads();

  const int wave = tid >> 6, lane = tid & 63;
  const int lr = lane & 15, lq = lane >> 4;
  const int m0 = blockIdx.x*128 + wave*32;
  constexpr int NBN = N/16;
  f32x4 acc[2][NBN];
#pragma unroll
  for (int i = 0; i < 2; i++)
#pragma unroll
    for (int j = 0; j < NBN; j++) acc[i][j] = (f32x4){0.f,0.f,0.f,0.f};

  const int r0 = m0 + lr;
#pragma unroll
  for (int ks = 0; ks < K/32; ks++){
    const int k0 = ks*32 + lq*8;
    bfrag a0 = {0,0,0,0,0,0,0,0}, a1 = {0,0,0,0,0,0,0,0};
    if (r0 < M)      a0 = *(const bfrag*)&A[(size_t)r0*K + k0];
    if (r0 + 16 < M) a1 = *(const bfrag*)&A[(size_t)(r0+16)*K + k0];
#pragma unroll
    for (int nb = 0; nb < NBN; nb++){
      bfrag bv = *(const bfrag*)&lds[(nb*16 + lr)*KP + k0];
      acc[0][nb] = __builtin_amdgcn_mfma_f32_16x16x32_bf16(a0, bv, acc[0][nb], 0, 0, 0);
      acc[1][nb] = __builtin_amdgcn_mfma_f32_16x16x32_bf16(a1, bv, acc[1][nb], 0, 0, 0);
    }
  }

  float sc = 0.f;
  if (MODE == EPI_ACC || MODE == EPI_FIN){
    float al = alphaPtr[0];
    sc = (MODE == EPI_FIN) ? al : (1.0f - al);
  }

#pragma unroll
  for (int mb = 0; mb < 2; mb++){
    const int rowb = m0 + mb*16 + lq*4;
#pragma unroll
    for (int nb = 0; nb < NBN; nb++){
      const int col = nb*16 + lr;
      const float bvv = bias ? bias[col] : 0.f;
#pragma unroll
      for (int r = 0; r < 4; r++){
        const int row = rowb + r;
        if (row >= M) continue;
        const size_t oi = (size_t)row*N + col;
        float v = silu_f(acc[mb][nb][r] + bvv);
        if (MODE == EPI_MUL){
          v *= b2f(aux[oi]);
          outB[oi] = f2b(v);
        } else if (MODE == EPI_ADD){
          if (aux) v += b2f(aux[oi]);
          outB[oi] = f2b(v);
        } else if (MODE == EPI_ACC){
          v += b2f(aux[oi]);
          accF[oi] += sc*v;
        } else {
          v += b2f(aux[oi]);
          outF[oi] = sc*v + accF[oi];
        }
      }
    }
  }
}

extern "C" void kernel_launch(void* const* d_in, const int* in_sizes, int n_in,
                              void* d_out, int out_size, void* d_ws, size_t ws_size,
                              hipStream_t stream)
{
  const float* x     = (const float*)d_in[0];
  const float* rbf   = (const float*)d_in[1];
  const float* sbf   = (const float*)d_in[2];
  const int*   ikj   = (const int*)d_in[3];
  const int*   iji   = (const int*)d_in[4];
  const int*   bt    = (const int*)d_in[5];
  const float* alphaP= (const float*)d_in[6];
  const float* Wrbf1 = (const float*)d_in[8];
  const float* Wrbf2 = (const float*)d_in[9];
  const float* Wsbf1 = (const float*)d_in[10];
  const float* Wsbf2 = (const float*)d_in[11];
  const float* Wkj   = (const float*)d_in[12];
  const float* bkj   = (const float*)d_in[13];
  const float* Wji   = (const float*)d_in[14];
  const float* bji   = (const float*)d_in[15];
  const float* Wdown = (const float*)d_in[16];
  const float* Wup   = (const float*)d_in[17];
  const float* Wbs1  = (const float*)d_in[18];
  const float* bbs1  = (const float*)d_in[19];
  const float* Wbs2  = (const float*)d_in[20];
  const float* bbs2  = (const float*)d_in[21];
  const float* Wlin  = (const float*)d_in[22];
  const float* blin  = (const float*)d_in[23];
  const float* Was1  = (const float*)d_in[24];
  const float* bas1  = (const float*)d_in[25];
  const float* Was2  = (const float*)d_in[26];
  const float* bas2  = (const float*)d_in[27];

  const int E = in_sizes[5];
  const int T = in_sizes[3];
  const int H = 128, I = 64;
  const size_t EH = (size_t)E*H, EI = (size_t)E*I;
  const int mt = (E + 127)/128;

  TW tw{Wkj, Wdown, Wji, Wup, Wbs1, Wbs2, Wlin, Was1, Was2, (u16*)0};

  // ---------- batched arena (fits in R2's proven 334.1 MB footprint) ----------
  {
    char* ws = (char*)d_ws;
    size_t off = 0;
    auto arena = [&](size_t bytes)->size_t{
      size_t o = off; off += (bytes + 255) & ~(size_t)255; return o;
    };
    size_t oWT   = arena((size_t)WT_TOTAL*2);   // 1.33 MB
    size_t oXB   = arena(EH*2);                 // 25.6 MB
    size_t oXKJ  = arena(EI*2);                 // 12.8 MB
    size_t oAGGB = arena(7*EI*2);               // 89.6 MB (persists into chain)
    size_t oBUF  = arena(2*(4*EH*2));           // 204.8 MB: BufA(4EH)+BufB(4EH)
    // pre-chain aliases inside BUF:
    //   AGG  fp32 6*EI*4 = 153.6 MB at BUF+0   (RBF2 dead before memset)
    //   S1   fp32 T*8*4  = 19.2 MB  at BUF+153.6
    //   RBF2 bf16 EH*2   = 25.6 MB  at BUF+0   (dead after KJ)
    //   TMP  bf16 EH*2   = 25.6 MB  at BUF+172.8 (dead after DOWN)

    if (off <= ws_size){
      u16*   WTb  = (u16*)(ws + oWT);
      u16*   XB   = (u16*)(ws + oXB);
      u16*   XKJ  = (u16*)(ws + oXKJ);
      u16*   AGGB = (u16*)(ws + oAGGB);
      char*  BUF  = ws + oBUF;
      u16*   BufA = (u16*)BUF;                       // 4EH bf16
      u16*   BufB = (u16*)(BUF + 4*EH*2);            // 4EH bf16
      float* AGG  = (float*)BUF;
      float* S1   = (float*)(BUF + 6*EI*4);
      u16*   RBF2 = (u16*)BUF;
      u16*   TMP  = (u16*)(BUF + 6*EI*4 + (size_t)T*8*4);

      tw.dst = WTb;
      hipLaunchKernelGGL(k_transpose, dim3(64, 44, 1), dim3(256, 1, 1), 0, stream, tw);
      k_f2b<<<dim3((int)((EH + 255)/256)), dim3(256), 0, stream>>>(x, XB, (int)EH);
      k_rbf<<<dim3((int)((EH + 255)/256)), dim3(256), 0, stream>>>(rbf, Wrbf1, Wrbf2, RBF2, E);
      // t = silu(x@W_kj+b)*rbf2 -> TMP
      k_gemmb<0,128,128><<<dim3(mt,1), dim3(256), 0, stream>>>(XB,0, WTb+OFF_KJ,0, bkj,0, RBF2,0, TMP,0, 0, E);
      // x_kj = silu(t@W_down) -> XKJ
      k_gemmb<1,64,128><<<dim3(mt,1), dim3(256), 0, stream>>>(TMP,0, WTb+OFF_DOWN,0, (const float*)0,0, (const u16*)0,0, XKJ,0, 0, E);
      k_s1<<<dim3((T + 255)/256), dim3(256), 0, stream>>>(sbf, Wsbf1, S1, T);
      hipMemsetAsync(BUF, 0, 6*EI*4, stream);
      k_triplet<<<dim3((int)(((size_t)T*64 + 255)/256)), dim3(256), 0, stream>>>(ikj, iji, bt, S1, Wsbf2, XKJ, AGG, T, E);
      k_cvt<<<dim3((int)((EI + 255)/256)), dim3(256), 0, stream>>>(AGG, AGGB, (int)EI);

      // chain in 2 groups (slices 0-3, then 4-6; c=6 -> weights b=5, agg slot 6)
      for (int g = 0; g < 2; g++){
        const int s0  = g ? 4 : 0;
        const int nsl = g ? 3 : 4;
        dim3 gr(mt, nsl);
        // U:   t1 = silu(agg_c @ W_up)               -> BufA
        k_gemmb<1,128,64><<<gr, dim3(256), 0, stream>>>(AGGB + (size_t)s0*EI,EI, WTb+OFF_UP,8192, (const float*)0,0, (const u16*)0,0, BufA,EH, s0, E);
        // JI:  h = silu(x@W_ji+b) + t1               -> BufB
        k_gemmb<1,128,128><<<gr, dim3(256), 0, stream>>>(XB,0, WTb+OFF_JI,16384, bji,128, BufA,EH, BufB,EH, s0, E);
        // BS1: t = silu(h@W_bs1+b)                   -> BufA
        k_gemmb<1,128,128><<<gr, dim3(256), 0, stream>>>(BufB,EH, WTb+OFF_BS1,16384, bbs1,128, (const u16*)0,0, BufA,EH, s0, E);
        // BS2: h = h + silu(t@W_bs2+b)               -> BufB (in-place aux)
        k_gemmb<1,128,128><<<gr, dim3(256), 0, stream>>>(BufA,EH, WTb+OFF_BS2,16384, bbs2,128, BufB,EH, BufB,EH, s0, E);
        // LIN: h2 = silu(h@W_lin+b) + x              -> BufA
        k_gemmb<1,128,128><<<gr, dim3(256), 0, stream>>>(BufB,EH, WTb+OFF_LIN,16384, blin,128, XB,0, BufA,EH, s0, E);
        // AS1: t2 = silu(h2@W_as1+b)                 -> BufB
        k_gemmb<1,128,128><<<gr, dim3(256), 0, stream>>>(BufA,EH, WTb+OFF_AS1,16384, bas1,128, (const u16*)0,0, BufB,EH, s0, E);
        // AS2: out_c = h2 + silu(t2@W_as2+b)         -> BufA (in-place aux)
        k_gemmb<1,128,128><<<gr, dim3(256), 0, stream>>>(BufB,EH, WTb+OFF_AS2,16384, bas2,128, BufA,EH, BufA,EH, s0, E);
        // fold group into d_out
        k_red<<<dim3((int)((EH/4 + 255)/256)), dim3(256), 0, stream>>>(BufA, alphaP, (float*)d_out, EH, nsl, g ? 1 : 0, g ? 1 : 0);
      }
      (void)n_in; (void)out_size;
      return;
    }
  }

  // ---------- legacy fallback (verified path) ----------
  {
    char* ws = (char*)d_ws;
    size_t off = 0;
    auto arena = [&](size_t bytes)->size_t{
      size_t o = off; off += (bytes + 255) & ~(size_t)255; return o;
    };
    size_t oWT   = arena((size_t)WT_TOTAL*2);
    size_t oXB   = arena(EH*2);
    size_t oR0   = arena(EH*2);
    size_t oR1   = arena(EH*2);
    size_t oXKJ  = arena(EI*2);
    size_t oAGG  = arena(6*EI*4);
    size_t oAGGB = arena(7*EI*2);
    if (off > ws_size) return;

    u16*   WTb  = (u16*)(ws + oWT);
    u16*   XB   = (u16*)(ws + oXB);
    u16*   R0   = (u16*)(ws + oR0);
    u16*   R1   = (u16*)(ws + oR1);
    u16*   XKJ  = (u16*)(ws + oXKJ);
    float* AGG  = (float*)(ws + oAGG);
    u16*   AGGB = (u16*)(ws + oAGGB);
    float* ACC  = (float*)(ws + oAGG);
    float* S1   = (float*)(ws + oR0);

    tw.dst = WTb;
    hipLaunchKernelGGL(k_transpose, dim3(64, 44, 1), dim3(256, 1, 1), 0, stream, tw);
    k_f2b<<<dim3((int)((EH + 255)/256)), dim3(256), 0, stream>>>(x, XB, (int)EH);
    k_rbf<<<dim3((int)((EH + 255)/256)), dim3(256), 0, stream>>>(rbf, Wrbf1, Wrbf2, R0, E);
    k_gemm<EPI_MUL,128,128><<<dim3(mt), dim3(256), 0, stream>>>(XB, WTb + OFF_KJ, bkj, R0, nullptr, R1, nullptr, nullptr, E);
    k_gemm<EPI_ADD,64,128><<<dim3(mt), dim3(256), 0, stream>>>(R1, WTb + OFF_DOWN, nullptr, nullptr, nullptr, XKJ, nullptr, nullptr, E);
    k_s1<<<dim3((T + 255)/256), dim3(256), 0, stream>>>(sbf, Wsbf1, S1, T);
    hipMemsetAsync(ws + oAGG, 0, 6*EI*4, stream);
    k_triplet<<<dim3((int)(((size_t)T*64 + 255)/256)), dim3(256), 0, stream>>>(ikj, iji, bt, S1, Wsbf2, XKJ, AGG, T, E);
    k_cvt<<<dim3((int)((EI + 255)/256)), dim3(256), 0, stream>>>(AGG, AGGB, (int)EI);
    hipMemsetAsync(ws + oAGG, 0, EH*4, stream);

    for (int c = 0; c < 7; c++){
      const int b    = (c < 6) ? c : 5;
      const int slot = (c < 6) ? c : 6;
      const u16* aggA = AGGB + (size_t)slot*EI;
      k_gemm<EPI_ADD,128,64><<<dim3(mt), dim3(256), 0, stream>>>(aggA, WTb + OFF_UP + b*8192, nullptr, nullptr, nullptr, R0, nullptr, nullptr, E);
      k_gemm<EPI_ADD,128,128><<<dim3(mt), dim3(256), 0, stream>>>(XB, WTb + OFF_JI + b*16384, bji + b*128, R0, nullptr, R1, nullptr, nullptr, E);
      k_gemm<EPI_ADD,128,128><<<dim3(mt), dim3(256), 0, stream>>>(R1, WTb + OFF_BS1 + b*16384, bbs1 + b*128, nullptr, nullptr, R0, nullptr, nullptr, E);
      k_gemm<EPI_ADD,128,128><<<dim3(mt), dim3(256), 0, stream>>>(R0, WTb + OFF_BS2 + b*16384, bbs2 + b*128, R1, nullptr, R1, nullptr, nullptr, E);
      k_gemm<EPI_ADD,128,128><<<dim3(mt), dim3(256), 0, stream>>>(R1, WTb + OFF_LIN + b*16384, blin + b*128, XB, nullptr, R0, nullptr, nullptr, E);
      k_gemm<EPI_ADD,128,128><<<dim3(mt), dim3(256), 0, stream>>>(R0, WTb + OFF_AS1 + b*16384, bas1 + b*128, nullptr, nullptr, R1, nullptr, nullptr, E);
      if (c < 6)
        k_gemm<EPI_ACC,128,128><<<dim3(mt), dim3(256), 0, stream>>>(R1, WTb + OFF_AS2 + b*16384, bas2 + b*128, R0, ACC, nullptr, nullptr, alphaP, E);
      else
        k_gemm<EPI_FIN,128,128><<<dim3(mt), dim3(256), 0, stream>>>(R1, WTb + OFF_AS2 + b*16384, bas2 + b*128, R0, ACC, nullptr, (float*)d_out, alphaP, E);
    }
  }
  (void)n_in; (void)out_size;
}